// Round 3
// baseline (473.735 us; speedup 1.0000x reference)
//
#include <hip/hip_runtime.h>

// SpikingSiameseNetwork forward, MI355X/gfx950.
// Pipeline: prep(weight 3-way bf16 split) -> GEMM1(all t) -> LIF1 scan ->
//           GEMM2(all t) -> LIF2 scan -> normalize+mean epilogue.
// Numerics: activations are exactly {0,1} (exact in bf16); weights split into
// 3 bf16 parts summed in the fp32 MFMA accumulator => ~fp32-GEMM-exact.
// R2: T2 XOR-swizzle (bank conflicts 2.9e7 -> 0, verified).
// R3: 256-tile 8-wave schedule with T14 load-early/write-late split +
//     phased MFMA clusters + T5 setprio; one barrier per K-chunk.

typedef short bf16x8 __attribute__((ext_vector_type(8)));
typedef float f32x4 __attribute__((ext_vector_type(4)));

#define RBIG 51200  // BS(2048) * T(25)

// ---------------- prep: split fp32 weights into 3 bf16 parts --------------
// W1s layout: [path][256][s*512 + k]  (n-major rows of length 1536)
// W2s layout: [path][128][s*256 + k]  (rows of length 768)
__global__ void prep_w(const float* __restrict__ Wa1, const float* __restrict__ Wv1,
                       const float* __restrict__ Wa2, const float* __restrict__ Wv2,
                       unsigned short* __restrict__ W1s, unsigned short* __restrict__ W2s) {
    int idx = blockIdx.x * 256 + threadIdx.x;  // total 327680 exactly
    float w;
    unsigned short* dst;
    int K, k;
    if (idx < 262144) {
        int p = idx >> 17, rem = idx & 131071;
        int n = rem >> 9; k = rem & 511; K = 512;
        const float* src = p ? Wv1 : Wa1;
        w = src[(size_t)n * 512 + k];
        dst = W1s + (size_t)p * 256 * 1536 + (size_t)n * 1536;
    } else {
        int j = idx - 262144;
        int p = j >> 15, rem = j & 32767;
        int n = rem >> 8; k = rem & 255; K = 256;
        const float* src = p ? Wv2 : Wa2;
        w = src[(size_t)n * 256 + k];
        dst = W2s + (size_t)p * 128 * 768 + (size_t)n * 768;
    }
    // exact splits: hi = trunc16(w); mid = trunc16(w-hi); lo = trunc16(residual)
    unsigned int u  = __float_as_uint(w);
    unsigned int hi = u & 0xFFFF0000u;
    float r1 = w - __uint_as_float(hi);         // exact
    unsigned int mi = __float_as_uint(r1) & 0xFFFF0000u;
    float r2 = r1 - __uint_as_float(mi);        // exact
    dst[k]         = (unsigned short)(hi >> 16);
    dst[K + k]     = (unsigned short)(mi >> 16);
    dst[2 * K + k] = (unsigned short)(__float_as_uint(r2) >> 16);
}

// ---------------- GEMM: C[51200 x NT] = A[51200 x KSRC] * W'^T -------------
// BM=256 x BN=NT tile, BK=64, 8 waves (WM x WN), 16x16x32 bf16 MFMA.
// K_eff = 3*KSRC; A staged once per kb, reused for the 3 weight splits.
// Schedule per chunk: [issue global loads c+1] [phases: ds_read+MFMA over
// buf(c)] [ds_write c+1 -> other buf] [barrier]. Writes overlap other waves'
// compute; safety: readers of the written buffer passed the previous barrier.
template <int KSRC, int NT, int WM, int WN, bool AF32>
__global__ __launch_bounds__(512, 2) void gemm8(
    const void* __restrict__ A0, const void* __restrict__ A1,
    const unsigned short* __restrict__ Ws, float* __restrict__ C) {
    constexpr int BM  = 256, BN = NT;
    constexpr int KE  = 3 * KSRC;
    constexpr int NKB = KSRC / 64;
    constexpr int NC  = 3 * NKB;
    constexpr int MFR = BM / WM / 16;   // M fragments per wave
    constexpr int NFR = BN / WN / 16;   // N fragments per wave
    constexpr int NPH = MFR / 2;        // phases (2 M-frags each)
    constexpr int NBB = BN * 64 / 8 / 512;  // uint4 slots per thread for B

    __shared__ unsigned short As[2][BM * 64];
    __shared__ unsigned short Bs[2][BN * 64];

    const int tid  = threadIdx.x;
    const int bx   = blockIdx.x, bz = blockIdx.y;
    const int lane = tid & 63, wave = tid >> 6;
    const int wm   = wave / WN, wn = wave % WN;
    const size_t row0 = (size_t)bx * BM;
    const unsigned short* Wp = Ws + (size_t)bz * NT * KE;

    f32x4 acc[MFR][NFR];
    f32x4 zz = {0.f, 0.f, 0.f, 0.f};
#pragma unroll
    for (int i = 0; i < MFR; ++i)
#pragma unroll
        for (int j = 0; j < NFR; ++j) acc[i][j] = zz;

    // ---- staging helpers (load -> regs, write -> LDS swizzled) ----
    auto loadB = [&](int kb, int s, uint4 (&r)[NBB]) {
        const unsigned short* Bg = Wp + (size_t)s * KSRC + (size_t)kb * 64;
#pragma unroll
        for (int j = 0; j < NBB; ++j) {
            int slot = tid + j * 512;
            int row = slot >> 3, c8 = (slot & 7) << 3;
            r[j] = *(const uint4*)(Bg + (size_t)row * KE + c8);
        }
    };
    auto writeB = [&](int buf, uint4 (&r)[NBB]) {
#pragma unroll
        for (int j = 0; j < NBB; ++j) {
            int slot = tid + j * 512;
            int row = slot >> 3, c8 = (slot & 7) << 3;
            int idx = (row * 64 + c8) ^ ((row & 7) << 3);
            *(uint4*)&Bs[buf][idx] = r[j];
        }
    };
    auto loadAf = [&](int kb, float4 (&r)[8]) {  // fp32 source, 4 pairs
        const float* Ag = (const float*)(bz ? A1 : A0);
#pragma unroll
        for (int j = 0; j < 4; ++j) {
            int pi = tid + j * 512;             // pair index, 8 pairs/row
            int row = pi >> 3, c = (pi & 7) << 3;
            const float* p = Ag + (row0 + row) * KSRC + kb * 64 + c;
            r[2 * j]     = *(const float4*)(p);
            r[2 * j + 1] = *(const float4*)(p + 4);
        }
    };
    auto writeAf = [&](int buf, float4 (&r)[8]) {
#pragma unroll
        for (int j = 0; j < 4; ++j) {
            int pi = tid + j * 512;
            int row = pi >> 3, c = (pi & 7) << 3;
            float4 v0 = r[2 * j], v1 = r[2 * j + 1];
            uint4 u;
            u.x = (__float_as_uint(v0.y) & 0xFFFF0000u) | (__float_as_uint(v0.x) >> 16);
            u.y = (__float_as_uint(v0.w) & 0xFFFF0000u) | (__float_as_uint(v0.z) >> 16);
            u.z = (__float_as_uint(v1.y) & 0xFFFF0000u) | (__float_as_uint(v1.x) >> 16);
            u.w = (__float_as_uint(v1.w) & 0xFFFF0000u) | (__float_as_uint(v1.z) >> 16);
            int idx = (row * 64 + c) ^ ((row & 7) << 3);
            *(uint4*)&As[buf][idx] = u;
        }
    };
    auto loadAu = [&](int kb, uint4 (&r)[4]) {   // bf16 source
        const unsigned short* Ag = (const unsigned short*)(bz ? A1 : A0);
#pragma unroll
        for (int j = 0; j < 4; ++j) {
            int slot = tid + j * 512;
            int row = slot >> 3, c8 = (slot & 7) << 3;
            r[j] = *(const uint4*)(Ag + (row0 + row) * KSRC + kb * 64 + c8);
        }
    };
    auto writeAu = [&](int buf, uint4 (&r)[4]) {
#pragma unroll
        for (int j = 0; j < 4; ++j) {
            int slot = tid + j * 512;
            int row = slot >> 3, c8 = (slot & 7) << 3;
            int idx = (row * 64 + c8) ^ ((row & 7) << 3);
            *(uint4*)&As[buf][idx] = r[j];
        }
    };

    // ---- prologue: stage chunk 0 ----
    {
        uint4 bR[NBB];
        loadB(0, 0, bR);
        if constexpr (AF32) {
            float4 aR[8];
            loadAf(0, aR);
            writeAf(0, aR);
        } else {
            uint4 aR[4];
            loadAu(0, aR);
            writeAu(0, aR);
        }
        writeB(0, bR);
    }
    __syncthreads();

    const int swz = (lane & 7) << 3;
    const int ko0 = (lane >> 4) << 3;
    const int rfr = lane & 15;

    int kb = 0, s = 0;
    for (int c = 0; c < NC; ++c) {
        int s1 = (s == 2) ? 0 : s + 1;
        int kb1 = (s1 == 0) ? kb + 1 : kb;
        const bool haveNext = (c + 1 < NC);

        // issue next-chunk loads early (T14): in flight across the phases
        uint4 bR[NBB];
        float4 aRf[8];
        uint4 aRu[4];
        if (haveNext) {
            loadB(kb1, s1, bR);
            if (s1 == 0) {
                if constexpr (AF32) loadAf(kb1, aRf);
                else                loadAu(kb1, aRu);
            }
        }

        // phased compute over current buffers
        const unsigned short* Ab = As[kb & 1];
        const unsigned short* Bb = Bs[c & 1];
        bf16x8 bb[NFR][2];
#pragma unroll
        for (int ph = 0; ph < NPH; ++ph) {
            if (ph == 0) {
#pragma unroll
                for (int ni = 0; ni < NFR; ++ni)
#pragma unroll
                    for (int ks = 0; ks < 2; ++ks) {
                        int Rn = wn * (BN / WN) + ni * 16 + rfr;
                        bb[ni][ks] = *(const bf16x8*)&Bb[(Rn * 64 + ks * 32 + ko0) ^ swz];
                    }
            }
            bf16x8 af[2][2];
#pragma unroll
            for (int q = 0; q < 2; ++q)
#pragma unroll
                for (int ks = 0; ks < 2; ++ks) {
                    int Rm = wm * (BM / WM) + (2 * ph + q) * 16 + rfr;
                    af[q][ks] = *(const bf16x8*)&Ab[(Rm * 64 + ks * 32 + ko0) ^ swz];
                }
            __builtin_amdgcn_s_setprio(1);
#pragma unroll
            for (int q = 0; q < 2; ++q)
#pragma unroll
                for (int ni = 0; ni < NFR; ++ni)
#pragma unroll
                    for (int ks = 0; ks < 2; ++ks)
                        acc[2 * ph + q][ni] = __builtin_amdgcn_mfma_f32_16x16x32_bf16(
                            af[q][ks], bb[ni][ks], acc[2 * ph + q][ni], 0, 0, 0);
            __builtin_amdgcn_s_setprio(0);
        }

        // write next chunk to the other buffers (overlaps nothing we read now)
        if (haveNext) {
            if (s1 == 0) {
                if constexpr (AF32) writeAf(kb1 & 1, aRf);
                else                writeAu(kb1 & 1, aRu);
            }
            writeB((c + 1) & 1, bR);
        }
        __syncthreads();
        kb = kb1; s = s1;
    }

    // epilogue: C/D layout col=lane&15, row=(lane>>4)*4+reg (m89-verified)
    float* Cp = C + (size_t)bz * RBIG * NT;
    int r4 = ((lane >> 4) << 2), cl = lane & 15;
#pragma unroll
    for (int mi = 0; mi < MFR; ++mi)
#pragma unroll
        for (int ni = 0; ni < NFR; ++ni) {
            size_t col = (size_t)wn * (BN / WN) + ni * 16 + cl;
#pragma unroll
            for (int j = 0; j < 4; ++j) {
                size_t row = row0 + wm * (BM / WM) + mi * 16 + r4 + j;
                Cp[row * NT + col] = acc[mi][ni][j];
            }
        }
}

// ---------------- LIF layer 1: scan over t, emit bf16 spikes ---------------
// cur layout [p][rho][256]; spikes packed 2/bf16 per u32. thread d -> h=2d,2d+1
__global__ void lif1_k(const float* __restrict__ cur, const float* __restrict__ ba1,
                       const float* __restrict__ bv1, unsigned int* __restrict__ spk) {
    int r = blockIdx.x, p = blockIdx.y, d = threadIdx.x;  // 128 threads
    const float* c0 = cur + ((size_t)p * RBIG + (size_t)r * 25) * 256 + 2 * d;
    const float* bias = p ? bv1 : ba1;
    float b0 = bias[2 * d], b1 = bias[2 * d + 1];
    float2 cv[25];
#pragma unroll
    for (int t = 0; t < 25; ++t) cv[t] = *(const float2*)(c0 + (size_t)t * 256);
    unsigned int* sp = spk + ((size_t)p * RBIG + (size_t)r * 25) * 128 + d;
    float m0 = 0.f, m1 = 0.f;
#pragma unroll
    for (int t = 0; t < 25; ++t) {
        float r0 = (m0 > 1.f) ? 1.f : 0.f;  // reset from PREVIOUS mem
        float r1 = (m1 > 1.f) ? 1.f : 0.f;
        m0 = 0.9f * m0 + (cv[t].x + b0) - r0;
        m1 = 0.9f * m1 + (cv[t].y + b1) - r1;
        unsigned int w = (m0 > 1.f ? 0x3F80u : 0u) | (m1 > 1.f ? 0x3F800000u : 0u);
        sp[(size_t)t * 128] = w;
    }
}

// ---------------- LIF layer 2: scan over t, keep only t=24 spikes ----------
__global__ void lif2_k(const float* __restrict__ cur2, const float* __restrict__ ba2,
                       const float* __restrict__ bv2, float* __restrict__ spk2) {
    int r = blockIdx.x, p = blockIdx.y, d = threadIdx.x;  // 64 threads
    const float* c0 = cur2 + ((size_t)p * RBIG + (size_t)r * 25) * 128 + 2 * d;
    const float* bias = p ? bv2 : ba2;
    float b0 = bias[2 * d], b1 = bias[2 * d + 1];
    float2 cv[25];
#pragma unroll
    for (int t = 0; t < 25; ++t) cv[t] = *(const float2*)(c0 + (size_t)t * 128);
    float m0 = 0.f, m1 = 0.f;
#pragma unroll
    for (int t = 0; t < 25; ++t) {
        float r0 = (m0 > 1.f) ? 1.f : 0.f;
        float r1 = (m1 > 1.f) ? 1.f : 0.f;
        m0 = 0.9f * m0 + (cv[t].x + b0) - r0;
        m1 = 0.9f * m1 + (cv[t].y + b1) - r1;
    }
    float2 o;
    o.x = (m0 > 1.f) ? 1.f : 0.f;
    o.y = (m1 > 1.f) ? 1.f : 0.f;
    *(float2*)(spk2 + ((size_t)p * 2048 + r) * 128 + 2 * d) = o;
}

// ---------------- epilogue: concat -> L2 normalize -> mean over S ----------
// Sum of {0,1} spike squares is order-exact -> reduction reorder is safe.
__global__ void epi_k(const float* __restrict__ spk2, float* __restrict__ out) {
    int b = blockIdx.x, d = threadIdx.x;  // 256 threads, d = output dim
    int p = d >> 7, e = d & 127;
    __shared__ float part[4];
    float acc = 0.f;
    for (int s = 0; s < 8; ++s) {
        float v = spk2[((size_t)p * 2048 + (size_t)(b * 8 + s)) * 128 + e];
        float sq = v;  // v in {0,1} -> v*v == v
#pragma unroll
        for (int off = 32; off > 0; off >>= 1) sq += __shfl_down(sq, off);
        if ((d & 63) == 0) part[d >> 6] = sq;
        __syncthreads();
        float nrm = sqrtf(part[0] + part[1] + part[2] + part[3]);
        acc += v / fmaxf(nrm, 1e-12f);
        __syncthreads();  // protect part[] before next s
    }
    out[(size_t)b * 256 + d] = acc * 0.125f;
}

extern "C" void kernel_launch(void* const* d_in, const int* in_sizes, int n_in,
                              void* d_out, int out_size, void* d_ws, size_t ws_size,
                              hipStream_t stream) {
    const float* a_seq = (const float*)d_in[0];
    const float* v_seq = (const float*)d_in[1];
    const float* W_a1  = (const float*)d_in[2];
    const float* b_a1  = (const float*)d_in[3];
    const float* W_a2  = (const float*)d_in[4];
    const float* b_a2  = (const float*)d_in[5];
    const float* W_v1  = (const float*)d_in[6];
    const float* b_v1  = (const float*)d_in[7];
    const float* W_v2  = (const float*)d_in[8];
    const float* b_v2  = (const float*)d_in[9];

    // workspace layout (needs ~161.4 MB)
    char* ws = (char*)d_ws;
    unsigned short* W1s  = (unsigned short*)(ws);              // 1,572,864 B
    unsigned short* W2s  = (unsigned short*)(ws + 1572864);    //   393,216 B
    unsigned short* spk1 = (unsigned short*)(ws + 1966080);    // 52,428,800 B
    float*          curb = (float*)(ws + 54394880);            // 104,857,600 B (cur1; reused as cur2)
    float*          spk2 = (float*)(ws + 159252480);           // 2,097,152 B
    float*          out  = (float*)d_out;

    prep_w<<<1280, 256, 0, stream>>>(W_a1, W_v1, W_a2, W_v2, W1s, W2s);

    // layer 1: cur1[p][51200][256]   (BM=256, BN=256, 8 waves 2x4)
    gemm8<512, 256, 2, 4, true><<<dim3(200, 2), 512, 0, stream>>>(a_seq, v_seq, W1s, curb);
    lif1_k<<<dim3(2048, 2), 128, 0, stream>>>(curb, b_a1, b_v1, (unsigned int*)spk1);

    // layer 2: cur2[p][51200][128]   (BM=256, BN=128, 8 waves 4x2)
    gemm8<256, 128, 4, 2, false><<<dim3(200, 2), 512, 0, stream>>>(
        spk1, spk1 + (size_t)RBIG * 256, W2s, curb);
    lif2_k<<<dim3(2048, 2), 64, 0, stream>>>(curb, b_a2, b_v2, spk2);

    epi_k<<<256, 256, 0, stream>>>(spk2, out);
}

// Round 4
// 399.632 us; speedup vs baseline: 1.1854x; 1.1854x over previous
//
#include <hip/hip_runtime.h>

// SpikingSiameseNetwork forward, MI355X/gfx950.
// prep(3-way bf16 weight split) -> GEMM1 -> LIF1 -> GEMM2 -> LIF2+epilogue.
// Numerics: activations exactly {0,1} (exact in bf16); weights split into 3
// bf16 parts summed in fp32 MFMA accumulator => fp32-exact (absmax 0.0, R1-R3).
// R2: XOR swizzle -> bank conflicts 0 (verified). 148us gemm1.
// R3: 256-tile/8-wave FAILED: VGPR spill (WRITE_SIZE +31MB scratch) + 1
//     block/CU (128KB LDS) + 22% grid tail -> 233us. Schedule not disproven.
// R4: R3 schedule (load-early/write-late, phased MFMA+setprio, 1 barrier per
//     chunk) on R2 geometry (128-wide tiles, 256 thr, 64KB LDS, 2-3 blk/CU).

typedef short bf16x8 __attribute__((ext_vector_type(8)));
typedef float f32x4 __attribute__((ext_vector_type(4)));

#define RBIG 51200  // BS(2048) * T(25)

// ---------------- prep: split fp32 weights into 3 bf16 parts --------------
__global__ void prep_w(const float* __restrict__ Wa1, const float* __restrict__ Wv1,
                       const float* __restrict__ Wa2, const float* __restrict__ Wv2,
                       unsigned short* __restrict__ W1s, unsigned short* __restrict__ W2s) {
    int idx = blockIdx.x * 256 + threadIdx.x;  // total 327680 exactly
    float w;
    unsigned short* dst;
    int K, k;
    if (idx < 262144) {
        int p = idx >> 17, rem = idx & 131071;
        int n = rem >> 9; k = rem & 511; K = 512;
        const float* src = p ? Wv1 : Wa1;
        w = src[(size_t)n * 512 + k];
        dst = W1s + (size_t)p * 256 * 1536 + (size_t)n * 1536;
    } else {
        int j = idx - 262144;
        int p = j >> 15, rem = j & 32767;
        int n = rem >> 8; k = rem & 255; K = 256;
        const float* src = p ? Wv2 : Wa2;
        w = src[(size_t)n * 256 + k];
        dst = W2s + (size_t)p * 128 * 768 + (size_t)n * 768;
    }
    unsigned int u  = __float_as_uint(w);
    unsigned int hi = u & 0xFFFF0000u;
    float r1 = w - __uint_as_float(hi);
    unsigned int mi = __float_as_uint(r1) & 0xFFFF0000u;
    float r2 = r1 - __uint_as_float(mi);
    dst[k]         = (unsigned short)(hi >> 16);
    dst[K + k]     = (unsigned short)(mi >> 16);
    dst[2 * K + k] = (unsigned short)(__float_as_uint(r2) >> 16);
}

// ---------------- GEMM: C[51200 x NT] = A * W'^T ---------------------------
// BM x BN block tile, BK=64, 4 waves (2x2, wave tile BM/2 x BN/2).
// Per chunk: [load c+1 -> regs] [ds_read frags(c) + MFMA, phased, setprio]
// [ds_write c+1 -> other buf] [barrier]. Buffer safety as R3 (passed).
template <int KSRC, int NT, int BN, int BM, int MINW, bool AF32>
__global__ __launch_bounds__(256, MINW) void gemmP(
    const void* __restrict__ A0, const void* __restrict__ A1,
    const unsigned short* __restrict__ Ws, float* __restrict__ C) {
    constexpr int KE  = 3 * KSRC;
    constexpr int NKB = KSRC / 64;
    constexpr int NC  = 3 * NKB;
    constexpr int MFR = BM / 2 / 16;
    constexpr int NFR = BN / 2 / 16;
    constexpr int NPH = (MFR + 1) / 2;
    constexpr int NBB = BN / 32;  // uint4 slots/thread for B tile
    constexpr int NAB = BM / 32;  // uint4 slots/thread (bf16 A) or f4-pairs (f32 A)

    __shared__ unsigned short As[2][BM * 64];
    __shared__ unsigned short Bs[2][BN * 64];

    const int tid  = threadIdx.x;
    const int bx   = blockIdx.x, by = blockIdx.y, bz = blockIdx.z;
    const int lane = tid & 63, wave = tid >> 6;
    const int wm   = wave >> 1, wn = wave & 1;
    const size_t row0 = (size_t)bx * BM;
    const unsigned short* Wp = Ws + (size_t)bz * NT * KE + (size_t)by * BN * KE;

    f32x4 acc[MFR][NFR];
    f32x4 zz = {0.f, 0.f, 0.f, 0.f};
#pragma unroll
    for (int i = 0; i < MFR; ++i)
#pragma unroll
        for (int j = 0; j < NFR; ++j) acc[i][j] = zz;

    auto loadB = [&](int kb, int s, uint4 (&r)[NBB]) {
        const unsigned short* Bg = Wp + (size_t)s * KSRC + (size_t)kb * 64;
#pragma unroll
        for (int j = 0; j < NBB; ++j) {
            int sl = tid + j * 256;
            int row = sl >> 3, c8 = (sl & 7) << 3;
            r[j] = *(const uint4*)(Bg + (size_t)row * KE + c8);
        }
    };
    auto writeB = [&](int buf, uint4 (&r)[NBB]) {
#pragma unroll
        for (int j = 0; j < NBB; ++j) {
            int sl = tid + j * 256;
            int row = sl >> 3, c8 = (sl & 7) << 3;
            *(uint4*)&Bs[buf][(row * 64 + c8) ^ ((row & 7) << 3)] = r[j];
        }
    };
    auto loadAf = [&](int kb, float4 (&r)[2 * NAB]) {
        const float* Ag = (const float*)(bz ? A1 : A0);
#pragma unroll
        for (int j = 0; j < NAB; ++j) {
            int pi = tid + j * 256;
            int row = pi >> 3, c = (pi & 7) << 3;
            const float* p = Ag + (row0 + row) * KSRC + kb * 64 + c;
            r[2 * j]     = *(const float4*)(p);
            r[2 * j + 1] = *(const float4*)(p + 4);
        }
    };
    auto writeAf = [&](int buf, float4 (&r)[2 * NAB]) {
#pragma unroll
        for (int j = 0; j < NAB; ++j) {
            int pi = tid + j * 256;
            int row = pi >> 3, c = (pi & 7) << 3;
            float4 v0 = r[2 * j], v1 = r[2 * j + 1];
            uint4 u;
            u.x = (__float_as_uint(v0.y) & 0xFFFF0000u) | (__float_as_uint(v0.x) >> 16);
            u.y = (__float_as_uint(v0.w) & 0xFFFF0000u) | (__float_as_uint(v0.z) >> 16);
            u.z = (__float_as_uint(v1.y) & 0xFFFF0000u) | (__float_as_uint(v1.x) >> 16);
            u.w = (__float_as_uint(v1.w) & 0xFFFF0000u) | (__float_as_uint(v1.z) >> 16);
            *(uint4*)&As[buf][(row * 64 + c) ^ ((row & 7) << 3)] = u;
        }
    };
    auto loadAu = [&](int kb, uint4 (&r)[NAB]) {
        const unsigned short* Ag = (const unsigned short*)(bz ? A1 : A0);
#pragma unroll
        for (int j = 0; j < NAB; ++j) {
            int sl = tid + j * 256;
            int row = sl >> 3, c8 = (sl & 7) << 3;
            r[j] = *(const uint4*)(Ag + (row0 + row) * KSRC + kb * 64 + c8);
        }
    };
    auto writeAu = [&](int buf, uint4 (&r)[NAB]) {
#pragma unroll
        for (int j = 0; j < NAB; ++j) {
            int sl = tid + j * 256;
            int row = sl >> 3, c8 = (sl & 7) << 3;
            *(uint4*)&As[buf][(row * 64 + c8) ^ ((row & 7) << 3)] = r[j];
        }
    };

    // prologue: stage chunk 0
    {
        uint4 bR[NBB];
        loadB(0, 0, bR);
        if constexpr (AF32) {
            float4 aR[2 * NAB];
            loadAf(0, aR);
            writeAf(0, aR);
        } else {
            uint4 aR[NAB];
            loadAu(0, aR);
            writeAu(0, aR);
        }
        writeB(0, bR);
    }
    __syncthreads();

    const int swz = (lane & 7) << 3;
    const int ko0 = (lane >> 4) << 3;
    const int rfr = lane & 15;

    int kb = 0, s = 0;
    for (int c = 0; c < NC; ++c) {
        int s1 = (s == 2) ? 0 : s + 1;
        int kb1 = (s1 == 0) ? kb + 1 : kb;
        const bool haveNext = (c + 1 < NC);

        // T14: issue next-chunk global loads before compute
        uint4 bR[NBB];
        float4 aRf[2 * NAB];
        uint4 aRu[NAB];
        if (haveNext) {
            loadB(kb1, s1, bR);
            if (s1 == 0) {
                if constexpr (AF32) loadAf(kb1, aRf);
                else                loadAu(kb1, aRu);
            }
        }

        const unsigned short* Ab = As[kb & 1];
        const unsigned short* Bb = Bs[c & 1];
        bf16x8 bb[NFR][2];
#pragma unroll
        for (int ph = 0; ph < NPH; ++ph) {
            if (ph == 0) {
#pragma unroll
                for (int ni = 0; ni < NFR; ++ni)
#pragma unroll
                    for (int ks = 0; ks < 2; ++ks) {
                        int Rn = wn * (BN / 2) + ni * 16 + rfr;
                        bb[ni][ks] = *(const bf16x8*)&Bb[(Rn * 64 + ks * 32 + ko0) ^ swz];
                    }
            }
            bf16x8 af[2][2];
#pragma unroll
            for (int q = 0; q < 2 && 2 * ph + q < MFR; ++q)
#pragma unroll
                for (int ks = 0; ks < 2; ++ks) {
                    int Rm = wm * (BM / 2) + (2 * ph + q) * 16 + rfr;
                    af[q][ks] = *(const bf16x8*)&Ab[(Rm * 64 + ks * 32 + ko0) ^ swz];
                }
            __builtin_amdgcn_s_setprio(1);
#pragma unroll
            for (int q = 0; q < 2 && 2 * ph + q < MFR; ++q)
#pragma unroll
                for (int ni = 0; ni < NFR; ++ni)
#pragma unroll
                    for (int ks = 0; ks < 2; ++ks)
                        acc[2 * ph + q][ni] = __builtin_amdgcn_mfma_f32_16x16x32_bf16(
                            af[q][ks], bb[ni][ks], acc[2 * ph + q][ni], 0, 0, 0);
            __builtin_amdgcn_s_setprio(0);
        }

        // write next chunk (other buffers); safe per single-barrier argument
        if (haveNext) {
            if (s1 == 0) {
                if constexpr (AF32) writeAf(kb1 & 1, aRf);
                else                writeAu(kb1 & 1, aRu);
            }
            writeB((c + 1) & 1, bR);
        }
        __syncthreads();
        kb = kb1; s = s1;
    }

    // epilogue: C/D layout col=lane&15, row=(lane>>4)*4+reg (m89-verified)
    float* Cp = C + (size_t)bz * RBIG * NT;
    int r4 = ((lane >> 4) << 2), cl = lane & 15;
#pragma unroll
    for (int mi = 0; mi < MFR; ++mi)
#pragma unroll
        for (int ni = 0; ni < NFR; ++ni) {
            size_t col = (size_t)by * BN + wn * (BN / 2) + ni * 16 + cl;
#pragma unroll
            for (int j = 0; j < 4; ++j) {
                size_t row = row0 + wm * (BM / 2) + mi * 16 + r4 + j;
                Cp[row * NT + col] = acc[mi][ni][j];
            }
        }
}

// ---------------- LIF layer 1: scan over t, emit bf16 spikes ---------------
__global__ void lif1_k(const float* __restrict__ cur, const float* __restrict__ ba1,
                       const float* __restrict__ bv1, unsigned int* __restrict__ spk) {
    int r = blockIdx.x, p = blockIdx.y, d = threadIdx.x;  // 128 threads
    const float* c0 = cur + ((size_t)p * RBIG + (size_t)r * 25) * 256 + 2 * d;
    const float* bias = p ? bv1 : ba1;
    float b0 = bias[2 * d], b1 = bias[2 * d + 1];
    float2 cv[25];
#pragma unroll
    for (int t = 0; t < 25; ++t) cv[t] = *(const float2*)(c0 + (size_t)t * 256);
    unsigned int* sp = spk + ((size_t)p * RBIG + (size_t)r * 25) * 128 + d;
    float m0 = 0.f, m1 = 0.f;
#pragma unroll
    for (int t = 0; t < 25; ++t) {
        float r0 = (m0 > 1.f) ? 1.f : 0.f;  // reset from PREVIOUS mem
        float r1 = (m1 > 1.f) ? 1.f : 0.f;
        m0 = 0.9f * m0 + (cv[t].x + b0) - r0;
        m1 = 0.9f * m1 + (cv[t].y + b1) - r1;
        unsigned int w = (m0 > 1.f ? 0x3F80u : 0u) | (m1 > 1.f ? 0x3F800000u : 0u);
        sp[(size_t)t * 128] = w;
    }
}

// -------- fused LIF2 + normalize + mean (one block per output batch b) -----
__global__ void tail_k(const float* __restrict__ cur2, const float* __restrict__ ba2,
                       const float* __restrict__ bv2, float* __restrict__ out) {
    int b = blockIdx.x, d = threadIdx.x;  // 256 threads, d = output dim
    int p = d >> 7, e = d & 127;
    const float* bias = p ? bv2 : ba2;
    float bo = bias[e];
    __shared__ float part[4];
    float acc = 0.f;
    for (int s = 0; s < 8; ++s) {
        int r = b * 8 + s;
        const float* c0 = cur2 + ((size_t)p * RBIG + (size_t)r * 25) * 128 + e;
        float cv[25];
#pragma unroll
        for (int t = 0; t < 25; ++t) cv[t] = c0[(size_t)t * 128];
        float m = 0.f;
#pragma unroll
        for (int t = 0; t < 25; ++t) {
            float rs = (m > 1.f) ? 1.f : 0.f;
            m = 0.9f * m + (cv[t] + bo) - rs;
        }
        float v = (m > 1.f) ? 1.f : 0.f;
        float sq = v;  // v in {0,1}: v*v == v; sum order-exact
#pragma unroll
        for (int off = 32; off > 0; off >>= 1) sq += __shfl_down(sq, off);
        if ((d & 63) == 0) part[d >> 6] = sq;
        __syncthreads();
        float nrm = sqrtf(part[0] + part[1] + part[2] + part[3]);
        acc += v / fmaxf(nrm, 1e-12f);
        __syncthreads();  // protect part[] before next s
    }
    out[(size_t)b * 256 + d] = acc * 0.125f;
}

extern "C" void kernel_launch(void* const* d_in, const int* in_sizes, int n_in,
                              void* d_out, int out_size, void* d_ws, size_t ws_size,
                              hipStream_t stream) {
    const float* a_seq = (const float*)d_in[0];
    const float* v_seq = (const float*)d_in[1];
    const float* W_a1  = (const float*)d_in[2];
    const float* b_a1  = (const float*)d_in[3];
    const float* W_a2  = (const float*)d_in[4];
    const float* b_a2  = (const float*)d_in[5];
    const float* W_v1  = (const float*)d_in[6];
    const float* b_v1  = (const float*)d_in[7];
    const float* W_v2  = (const float*)d_in[8];
    const float* b_v2  = (const float*)d_in[9];

    char* ws = (char*)d_ws;  // ~159.3 MB used
    unsigned short* W1s  = (unsigned short*)(ws);              // 1,572,864 B
    unsigned short* W2s  = (unsigned short*)(ws + 1572864);    //   393,216 B
    unsigned short* spk1 = (unsigned short*)(ws + 1966080);    // 52,428,800 B
    float*          curb = (float*)(ws + 54394880);            // 104,857,600 B
    float*          out  = (float*)d_out;

    prep_w<<<1280, 256, 0, stream>>>(W_a1, W_v1, W_a2, W_v2, W1s, W2s);

    // layer 1: cur1[p][51200][256]; BM=128, BN=128 (by=2 halves), 2 blk/CU
    gemmP<512, 256, 128, 128, 2, true><<<dim3(400, 2, 2), 256, 0, stream>>>(
        a_seq, v_seq, W1s, curb);
    lif1_k<<<dim3(2048, 2), 128, 0, stream>>>(curb, b_a1, b_v1, (unsigned int*)spk1);

    // layer 2: cur2[p][51200][128]; BM=64, 3 blk/CU, 1600 blocks
    gemmP<256, 128, 128, 64, 3, false><<<dim3(800, 1, 2), 256, 0, stream>>>(
        spk1, spk1 + (size_t)RBIG * 256, W2s, curb);

    tail_k<<<256, 256, 0, stream>>>(curb, b_a2, b_v2, out);
}